// Round 5
// baseline (57.432 us; speedup 1.0000x reference)
//
#include <hip/hip_runtime.h>
#include <cstdint>
#include <cstddef>

#define BS 8
#define NQ 16384
#define NG 1024
#define NC 5
#define NBC 40
#define THREADS 256
#define GRID 512            // 8 batches * 64 chunk-blocks; 2 blocks/CU -> co-resident
#define CSLOTS 64           // clist capacity per (bc, chunk)
#define SLACK 0.1514214f    // 0.1*sqrt(2) + 0.01 margin
#define FINF 3.0e38f

using u64 = unsigned long long;
#define AGENT __HIP_MEMORY_SCOPE_AGENT

// agent-scope (coherent-point) accessors for cross-block data
__device__ __forceinline__ float aload_f(const float* p) {
    return __hip_atomic_load(p, __ATOMIC_RELAXED, AGENT);
}
__device__ __forceinline__ void astore_f(float* p, float v) {
    __hip_atomic_store(p, v, __ATOMIC_RELAXED, AGENT);
}
__device__ __forceinline__ unsigned aload_u(const unsigned* p) {
    return __hip_atomic_load(p, __ATOMIC_RELAXED, AGENT);
}
__device__ __forceinline__ void astore_u(unsigned* p, unsigned v) {
    __hip_atomic_store(p, v, __ATOMIC_RELAXED, AGENT);
}
__device__ __forceinline__ u64 aload_u64(const u64* p) {
    return __hip_atomic_load(p, __ATOMIC_RELAXED, AGENT);
}
__device__ __forceinline__ void astore_u64(u64* p, u64 v) {
    __hip_atomic_store(p, v, __ATOMIC_RELAXED, AGENT);
}

// ---------- float top-4 (keep 4 smallest, sorted ascending) ----------
__device__ __forceinline__ void fce(float &x, float &y) {
    float lo = fminf(x, y), hi = fmaxf(x, y);
    x = lo; y = hi;
}
__device__ __forceinline__ void finsert(float k[4], float v) {
    float c = v, t;
    t = fminf(k[0], c); c = fmaxf(k[0], c); k[0] = t;
    t = fminf(k[1], c); c = fmaxf(k[1], c); k[1] = t;
    t = fminf(k[2], c); c = fmaxf(k[2], c); k[2] = t;
    k[3] = fminf(k[3], c);
}
__device__ __forceinline__ void fmerge4(float a[4], float b0, float b1, float b2, float b3) {
    float m0 = fminf(a[0], b3), m1 = fminf(a[1], b2), m2 = fminf(a[2], b1), m3 = fminf(a[3], b0);
    fce(m0, m2); fce(m1, m3); fce(m0, m1); fce(m2, m3);
    a[0] = m0; a[1] = m1; a[2] = m2; a[3] = m3;
}

// ---------- u64 keyed top-4 (exact, tie-break by low 32 = q) ----------
__device__ __forceinline__ void ce(u64 &x, u64 &y) {
    u64 lo = x < y ? x : y;
    u64 hi = x < y ? y : x;
    x = lo; y = hi;
}
__device__ __forceinline__ void merge4(u64 a[4], u64 b0, u64 b1, u64 b2, u64 b3) {
    u64 m0 = a[0] < b3 ? a[0] : b3;
    u64 m1 = a[1] < b2 ? a[1] : b2;
    u64 m2 = a[2] < b1 ? a[2] : b1;
    u64 m3 = a[3] < b0 ? a[3] : b0;
    ce(m0, m2); ce(m1, m3); ce(m0, m1); ce(m2, m3);
    a[0] = m0; a[1] = m1; a[2] = m2; a[3] = m3;
}
__device__ __forceinline__ void kinsert(u64 kk[4], float cost, unsigned q) {
    unsigned uu = __float_as_uint(cost);
    uu ^= ((unsigned)((int)uu >> 31)) | 0x80000000u;
    u64 k = ((u64)uu << 32) | q;
    if (k < kk[3]) { kk[3] = k; ce(kk[2], kk[3]); ce(kk[1], kk[2]); ce(kk[0], kk[1]); }
}

#define SOFTMAX5(lg, X0, X1, X2, X3, X4, S)                                     \
    float X0 = (lg)[0], X1 = (lg)[1], X2 = (lg)[2], X3 = (lg)[3], X4 = (lg)[4]; \
    {                                                                           \
        float mx_ = fmaxf(fmaxf(fmaxf(X0, X1), fmaxf(X2, X3)), X4);             \
        X0 = expf(X0 - mx_); X1 = expf(X1 - mx_); X2 = expf(X2 - mx_);          \
        X3 = expf(X3 - mx_); X4 = expf(X4 - mx_);                               \
    }                                                                           \
    float S = X0 + X1 + X2 + X3 + X4;

// per-batch flag barrier: NO RMWs. Arrival = release-store own flag;
// detection = wave 0 reads all 64 batch flags in parallel, __all-reduce.
// flags zeroed by the memset node before each replay.
__device__ __forceinline__ void batchbar(unsigned* flags, int b, int chunk, int tid) {
    __syncthreads();
    if (tid == 0)
        __hip_atomic_store(&flags[b * 64 + chunk], 1u, __ATOMIC_RELEASE, AGENT);
    if (tid < 64) {
        const unsigned* fp = &flags[b * 64 + tid];
        for (long s = 0; s < (1L << 22); ++s) {          // bounded spin safety net
            unsigned f = __hip_atomic_load(fp, __ATOMIC_RELAXED, AGENT);
            if (__all((int)(f != 0u))) break;
            __builtin_amdgcn_s_sleep(1);
        }
    }
    __syncthreads();
}

__global__ __launch_bounds__(THREADS, 2) void fused_kernel(
        const float* __restrict__ pred_coords,   // [BS][NQ][2]
        const float* __restrict__ logits,        // [BS][NQ][NC]
        const float* __restrict__ gt_coords,     // [BS][NG][2]
        const int*   __restrict__ gt_labels,     // [BS][NG]
        const int*   __restrict__ gt_masks,      // [BS][NG]
        unsigned*    __restrict__ bar0,          // [512] flags
        unsigned*    __restrict__ bar1,          // [512] flags
        unsigned*    __restrict__ ccount,        // [NBC][64]
        float*       __restrict__ partials,      // [BS][64][NC][4]
        u64*         __restrict__ clist,         // [NBC][64][CSLOTS]
        int*         __restrict__ out)           // [BS][4][NG]
{
    const int blk = blockIdx.x, tid = threadIdx.x;
    const int wv = tid >> 6, lane = tid & 63;
    const int b = blk >> 6, chunk = blk & 63;
    const int q = (chunk << 8) + tid;

    __shared__ float slds[4][NC][4];

    // ---------------- phase A: softmax once per q; block top-4 per class ----------------
    const float* lg = logits + ((size_t)b * NQ + q) * NC;
    SOFTMAX5(lg, x0, x1, x2, x3, x4, s);
    float p0 = x0 / s, p1 = x1 / s, p2 = x2 / s, p3 = x3 / s, p4 = x4 / s;

    {
        float nk[NC][4];
        nk[0][0] = -p0; nk[1][0] = -p1; nk[2][0] = -p2; nk[3][0] = -p3; nk[4][0] = -p4;
        #pragma unroll
        for (int c = 0; c < NC; ++c) { nk[c][1] = FINF; nk[c][2] = FINF; nk[c][3] = FINF; }
        #pragma unroll
        for (int d = 1; d < 64; d <<= 1) {
            #pragma unroll
            for (int c = 0; c < NC; ++c) {
                float b0 = __shfl_xor(nk[c][0], d, 64);
                float b1 = __shfl_xor(nk[c][1], d, 64);
                float b2 = __shfl_xor(nk[c][2], d, 64);
                float b3 = __shfl_xor(nk[c][3], d, 64);
                fmerge4(nk[c], b0, b1, b2, b3);
            }
        }
        if (lane == 0) {
            #pragma unroll
            for (int c = 0; c < NC; ++c)
                #pragma unroll
                for (int j = 0; j < 4; ++j) slds[wv][c][j] = nk[c][j];
        }
        __syncthreads();
        if (tid < NC) {                      // one thread per class finalizes
            float a[4] = {slds[0][tid][0], slds[0][tid][1], slds[0][tid][2], slds[0][tid][3]};
            #pragma unroll
            for (int w = 1; w < 4; ++w)
                fmerge4(a, slds[w][tid][0], slds[w][tid][1], slds[w][tid][2], slds[w][tid][3]);
            float* pp = partials + ((size_t)(b * 64 + chunk) * NC + tid) * 4;
            #pragma unroll
            for (int j = 0; j < 4; ++j) astore_f(&pp[j], a[j]);
        }
    }

    batchbar(bar0, b, chunk, tid);

    // ---------------- phase B: per-wave redundant threshold; ballot-rank compact ----------------
    float Tc[NC];
    {
        #pragma unroll
        for (int c = 0; c < NC; ++c) {
            const float* pp = partials + ((size_t)(b * 64 + lane) * NC + c) * 4;
            float a[4] = {FINF, FINF, FINF, FINF};
            #pragma unroll
            for (int j = 0; j < 4; ++j) finsert(a, aload_f(&pp[j]));
            #pragma unroll
            for (int d = 1; d < 64; d <<= 1) {
                float b0 = __shfl_xor(a[0], d, 64);
                float b1 = __shfl_xor(a[1], d, 64);
                float b2 = __shfl_xor(a[2], d, 64);
                float b3 = __shfl_xor(a[3], d, 64);
                fmerge4(a, b0, b1, b2, b3);
            }
            Tc[c] = -a[3] - SLACK;           // P4* - slack
        }
    }
    __shared__ unsigned wcnt[4];
    #pragma unroll
    for (int c = 0; c < NC; ++c) {
        float p = (c == 0) ? p0 : (c == 1) ? p1 : (c == 2) ? p2 : (c == 3) ? p3 : p4;
        bool pass = (p >= Tc[c]);
        u64 m = __ballot(pass);
        if (lane == 0) wcnt[wv] = (unsigned)__popcll(m);
        __syncthreads();
        unsigned pre = 0, tot = 0;
        #pragma unroll
        for (int w = 0; w < 4; ++w) { unsigned v = wcnt[w]; if (w < wv) pre += v; tot += v; }
        int bc = b * NC + c;
        if (pass) {
            unsigned rank = pre + (unsigned)__popcll(m & ((1ull << lane) - 1ull));
            if (rank < CSLOTS)
                astore_u64(&clist[((size_t)bc * 64 + chunk) * CSLOTS + rank],
                           ((u64)__float_as_uint(p) << 32) | (unsigned)q);
        }
        if (tid == 0) astore_u(&ccount[bc * 64 + chunk], tot);   // tot>CSLOTS = overflow flag
        __syncthreads();
    }

    batchbar(bar1, b, chunk, tid);

    // ---------------- phase C: exact keyed top-4 per gt (own batch; 1 gt/wave, 4 rounds) ----------------
    const float2* pc = reinterpret_cast<const float2*>(pred_coords) + (size_t)b * NQ;
    #pragma unroll
    for (int t = 0; t < 4; ++t) {
        int g = t * 256 + chunk * 4 + wv;
        int m = gt_masks[b * NG + g];
        u64 kk[4] = {~0ull, ~0ull, ~0ull, ~0ull};
        if (m) {
            int c  = gt_labels[b * NG + g];
            int bc = b * NC + c;
            float2 gc = reinterpret_cast<const float2*>(gt_coords)[(size_t)b * NG + g];
            float gx = gc.x, gy = gc.y, gb2 = gc.x * gc.x + gc.y * gc.y;
            unsigned n = aload_u(&ccount[bc * 64 + lane]);       // lane = source chunk
            u64 ov = __ballot(n > CSLOTS);
            if (ov == 0) {
                const u64* lst = clist + ((size_t)bc * 64 + lane) * CSLOTS;
                unsigned j = 0;
                for (; j + 2 <= n; j += 2) {                     // unroll-2: overlap L3 latency
                    u64 e0 = aload_u64(&lst[j]);
                    u64 e1 = aload_u64(&lst[j + 1]);
                    float pA = __uint_as_float((unsigned)(e0 >> 32));
                    unsigned qA = (unsigned)(e0 & 0xFFFFFFFFu);
                    float pB = __uint_as_float((unsigned)(e1 >> 32));
                    unsigned qB = (unsigned)(e1 & 0xFFFFFFFFu);
                    float2 cA = pc[qA], cB = pc[qB];
                    float dA = fmaxf(cA.x * cA.x + cA.y * cA.y + gb2 - 2.0f * (cA.x * gx + cA.y * gy), 0.0f);
                    float dB = fmaxf(cB.x * cB.x + cB.y * cB.y + gb2 - 2.0f * (cB.x * gx + cB.y * gy), 0.0f);
                    kinsert(kk, 0.1f * sqrtf(dA) - pA, qA);
                    kinsert(kk, 0.1f * sqrtf(dB) - pB, qB);
                }
                if (j < n) {
                    u64 e = aload_u64(&lst[j]);
                    float p = __uint_as_float((unsigned)(e >> 32));
                    unsigned qq = (unsigned)(e & 0xFFFFFFFFu);
                    float2 cq = pc[qq];
                    float d2 = fmaxf(cq.x * cq.x + cq.y * cq.y + gb2 - 2.0f * (cq.x * gx + cq.y * gy), 0.0f);
                    kinsert(kk, 0.1f * sqrtf(d2) - p, qq);
                }
            } else {
                // overflow fallback: exact brute scan (same numerics)
                for (int q2 = lane; q2 < NQ; q2 += 64) {
                    const float* lg2 = logits + ((size_t)b * NQ + q2) * NC;
                    SOFTMAX5(lg2, y0, y1, y2, y3, y4, s2);
                    float num = (c == 0) ? y0 : (c == 1) ? y1 : (c == 2) ? y2 : (c == 3) ? y3 : y4;
                    float p = num / s2;
                    float2 cq = pc[q2];
                    float d2 = fmaxf(cq.x * cq.x + cq.y * cq.y + gb2 - 2.0f * (cq.x * gx + cq.y * gy), 0.0f);
                    kinsert(kk, 0.1f * sqrtf(d2) - p, (unsigned)q2);
                }
            }
            #pragma unroll
            for (int d = 1; d < 64; d <<= 1) {
                u64 b0 = __shfl_xor(kk[0], d, 64);
                u64 b1 = __shfl_xor(kk[1], d, 64);
                u64 b2_ = __shfl_xor(kk[2], d, 64);
                u64 b3 = __shfl_xor(kk[3], d, 64);
                merge4(kk, b0, b1, b2_, b3);
            }
        }
        if (lane < 4) {
            u64 sel = (lane == 0) ? kk[0] : (lane == 1) ? kk[1] : (lane == 2) ? kk[2] : kk[3];
            int idx = m ? (int)(sel & 0xFFFFFFFFull) : lane;
            out[((size_t)(b * 4 + lane) << 10) + g] = idx;
        }
    }
}

extern "C" void kernel_launch(void* const* d_in, const int* in_sizes, int n_in,
                              void* d_out, int out_size, void* d_ws, size_t ws_size,
                              hipStream_t stream) {
    const float* pred_coords = (const float*)d_in[0];
    const float* pred_logits = (const float*)d_in[1];
    const float* gt_coords   = (const float*)d_in[2];
    const int*   gt_labels   = (const int*)d_in[3];
    const int*   gt_masks    = (const int*)d_in[4];
    int* out = (int*)d_out;

    char* ws = (char*)d_ws;
    unsigned* bar0     = (unsigned*)(ws + 0);        // 512 u32 flags
    unsigned* bar1     = (unsigned*)(ws + 2048);     // 512 u32 flags
    unsigned* ccount   = (unsigned*)(ws + 8192);     // 40*64 u32 (fully rewritten/run)
    float*    partials = (float*)(ws + 20480);       // 8*64*5*4 f32 (fully rewritten/run)
    u64*      clist    = (u64*)(ws + 65536);         // 40*64*64 u64 = 1.31 MB

    hipMemsetAsync(ws, 0, 4096, stream);             // zero barrier flags each replay
    fused_kernel<<<GRID, THREADS, 0, stream>>>(
        pred_coords, pred_logits, gt_coords, gt_labels, gt_masks,
        bar0, bar1, ccount, partials, clist, out);
}

// Round 6
// 40.729 us; speedup vs baseline: 1.4101x; 1.4101x over previous
//
#include <hip/hip_runtime.h>
#include <cstdint>
#include <cstddef>

#define BS 8
#define NQ 16384
#define NG 1024
#define NC 5
#define NBC 40
#define THREADS 256
#define CSLOTS 128          // clist capacity per (bc, chunk)
#define SLACK 0.1514214f    // 0.1*sqrt(2) + 0.01 margin
#define FINF 3.0e38f

using u64 = unsigned long long;

// ---------- float top-4 (keep 4 smallest, sorted ascending) ----------
__device__ __forceinline__ void fce(float &x, float &y) {
    float lo = fminf(x, y), hi = fmaxf(x, y);
    x = lo; y = hi;
}
__device__ __forceinline__ void fmerge4(float a[4], float b0, float b1, float b2, float b3) {
    float m0 = fminf(a[0], b3), m1 = fminf(a[1], b2), m2 = fminf(a[2], b1), m3 = fminf(a[3], b0);
    fce(m0, m2); fce(m1, m3); fce(m0, m1); fce(m2, m3);
    a[0] = m0; a[1] = m1; a[2] = m2; a[3] = m3;
}

// ---------- u64 keyed top-4 (exact, tie-break by low 32 = q) ----------
__device__ __forceinline__ void ce(u64 &x, u64 &y) {
    u64 lo = x < y ? x : y;
    u64 hi = x < y ? y : x;
    x = lo; y = hi;
}
__device__ __forceinline__ void merge4(u64 a[4], u64 b0, u64 b1, u64 b2, u64 b3) {
    u64 m0 = a[0] < b3 ? a[0] : b3;
    u64 m1 = a[1] < b2 ? a[1] : b2;
    u64 m2 = a[2] < b1 ? a[2] : b1;
    u64 m3 = a[3] < b0 ? a[3] : b0;
    ce(m0, m2); ce(m1, m3); ce(m0, m1); ce(m2, m3);
    a[0] = m0; a[1] = m1; a[2] = m2; a[3] = m3;
}
__device__ __forceinline__ void kinsert(u64 kk[4], float cost, unsigned q) {
    unsigned uu = __float_as_uint(cost);
    uu ^= ((unsigned)((int)uu >> 31)) | 0x80000000u;
    u64 k = ((u64)uu << 32) | q;
    if (k < kk[3]) { kk[3] = k; ce(kk[2], kk[3]); ce(kk[1], kk[2]); ce(kk[0], kk[1]); }
}

#define SOFTMAX5(lg, X0, X1, X2, X3, X4, S)                                     \
    float X0 = (lg)[0], X1 = (lg)[1], X2 = (lg)[2], X3 = (lg)[3], X4 = (lg)[4]; \
    {                                                                           \
        float mx_ = fmaxf(fmaxf(fmaxf(X0, X1), fmaxf(X2, X3)), X4);             \
        X0 = expf(X0 - mx_); X1 = expf(X1 - mx_); X2 = expf(X2 - mx_);          \
        X3 = expf(X3 - mx_); X4 = expf(X4 - mx_);                               \
    }                                                                           \
    float S = X0 + X1 + X2 + X3 + X4;

// ---------- kernel 1: softmax + LOCAL per-block threshold + compact ----------
// Correctness of local threshold: for any gt of class c, a top-4 query q* has
// p_c(q*) >= globalP4 - 0.1*sqrt(2) >= localP4(chunk) - 0.1*sqrt(2) > Tlocal.
__global__ __launch_bounds__(THREADS) void prune_kernel(
        const float* __restrict__ logits,        // [BS][NQ][NC]
        unsigned*    __restrict__ ccount,        // [NBC][64]
        u64*         __restrict__ clist)         // [NBC][CSLOTS][64]  (slot-major!)
{
    const int blk = blockIdx.x, tid = threadIdx.x;   // 512 blocks
    const int wv = tid >> 6, lane = tid & 63;
    const int b = blk >> 6, chunk = blk & 63;
    const int q = (chunk << 8) + tid;

    const float* lg = logits + ((size_t)b * NQ + q) * NC;
    SOFTMAX5(lg, x0, x1, x2, x3, x4, s);
    float p0 = x0 / s, p1 = x1 / s, p2 = x2 / s, p3 = x3 / s, p4 = x4 / s;

    // block-local top-4 of p per class (negated, ascending)
    __shared__ float slds[4][NC][4];
    __shared__ float Tsh[NC];
    {
        float nk[NC][4];
        nk[0][0] = -p0; nk[1][0] = -p1; nk[2][0] = -p2; nk[3][0] = -p3; nk[4][0] = -p4;
        #pragma unroll
        for (int c = 0; c < NC; ++c) { nk[c][1] = FINF; nk[c][2] = FINF; nk[c][3] = FINF; }
        #pragma unroll
        for (int d = 1; d < 64; d <<= 1) {
            #pragma unroll
            for (int c = 0; c < NC; ++c) {
                float b0 = __shfl_xor(nk[c][0], d, 64);
                float b1 = __shfl_xor(nk[c][1], d, 64);
                float b2 = __shfl_xor(nk[c][2], d, 64);
                float b3 = __shfl_xor(nk[c][3], d, 64);
                fmerge4(nk[c], b0, b1, b2, b3);
            }
        }
        if (lane == 0) {
            #pragma unroll
            for (int c = 0; c < NC; ++c)
                #pragma unroll
                for (int j = 0; j < 4; ++j) slds[wv][c][j] = nk[c][j];
        }
        __syncthreads();
        if (tid < NC) {
            float a[4] = {slds[0][tid][0], slds[0][tid][1], slds[0][tid][2], slds[0][tid][3]};
            #pragma unroll
            for (int w = 1; w < 4; ++w)
                fmerge4(a, slds[w][tid][0], slds[w][tid][1], slds[w][tid][2], slds[w][tid][3]);
            Tsh[tid] = -a[3] - SLACK;        // localP4 - slack
        }
        __syncthreads();
    }

    // ballot-rank compact into own chunk column (plain stores; no atomics)
    __shared__ unsigned wcnt[4];
    #pragma unroll
    for (int c = 0; c < NC; ++c) {
        float p = (c == 0) ? p0 : (c == 1) ? p1 : (c == 2) ? p2 : (c == 3) ? p3 : p4;
        bool pass = (p >= Tsh[c]);
        u64 m = __ballot(pass);
        if (lane == 0) wcnt[wv] = (unsigned)__popcll(m);
        __syncthreads();
        unsigned pre = 0, tot = 0;
        #pragma unroll
        for (int w = 0; w < 4; ++w) { unsigned v = wcnt[w]; if (w < wv) pre += v; tot += v; }
        int bc = b * NC + c;
        if (pass) {
            unsigned rank = pre + (unsigned)__popcll(m & ((1ull << lane) - 1ull));
            if (rank < CSLOTS)
                clist[((size_t)bc * CSLOTS + rank) * 64 + chunk] =
                    ((u64)__float_as_uint(p) << 32) | (unsigned)q;
        }
        if (tid == 0) ccount[bc * 64 + chunk] = tot;   // tot > CSLOTS = overflow flag
        __syncthreads();
    }
}

// ---------- kernel 2: exact keyed top-4 per gt (1 gt per wave) ----------
__global__ __launch_bounds__(THREADS) void match_kernel(
        const float* __restrict__ pred_coords,   // [BS][NQ][2]
        const float* __restrict__ logits,        // [BS][NQ][NC]
        const float* __restrict__ gt_coords,     // [BS][NG][2]
        const int*   __restrict__ gt_labels,     // [BS][NG]
        const int*   __restrict__ gt_masks,      // [BS][NG]
        const unsigned* __restrict__ ccount,     // [NBC][64]
        const u64*   __restrict__ clist,         // [NBC][CSLOTS][64]
        int*         __restrict__ out)           // [BS][4][NG]
{
    const int tid = threadIdx.x;
    const int wv = tid >> 6, lane = tid & 63;
    const int gidx = blockIdx.x * 4 + wv;        // 2048 blocks * 4 waves = 8192 gts
    const int b = gidx >> 10, g = gidx & 1023;

    int m = gt_masks[b * NG + g];
    u64 kk[4] = {~0ull, ~0ull, ~0ull, ~0ull};
    if (m) {
        int c  = gt_labels[b * NG + g];
        int bc = b * NC + c;
        float2 gc = reinterpret_cast<const float2*>(gt_coords)[(size_t)b * NG + g];
        float gx = gc.x, gy = gc.y, gb2 = gc.x * gc.x + gc.y * gc.y;
        const float2* pc = reinterpret_cast<const float2*>(pred_coords) + (size_t)b * NQ;
        unsigned n = ccount[bc * 64 + lane];     // lane = source chunk
        u64 ov = __ballot(n > CSLOTS);
        if (ov == 0) {
            const u64* lst = clist + (size_t)bc * CSLOTS * 64 + lane;
            for (unsigned j = 0; j < n; ++j) {
                u64 e = lst[j * 64];             // lane-coalesced read
                float p = __uint_as_float((unsigned)(e >> 32));
                unsigned qq = (unsigned)(e & 0xFFFFFFFFu);
                float2 cq = pc[qq];
                float d2 = fmaxf(cq.x * cq.x + cq.y * cq.y + gb2 - 2.0f * (cq.x * gx + cq.y * gy), 0.0f);
                kinsert(kk, 0.1f * sqrtf(d2) - p, qq);
            }
        } else {
            // overflow fallback: exact brute scan (same numerics)
            for (int q2 = lane; q2 < NQ; q2 += 64) {
                const float* lg2 = logits + ((size_t)b * NQ + q2) * NC;
                SOFTMAX5(lg2, y0, y1, y2, y3, y4, s2);
                float num = (c == 0) ? y0 : (c == 1) ? y1 : (c == 2) ? y2 : (c == 3) ? y3 : y4;
                float p = num / s2;
                float2 cq = pc[q2];
                float d2 = fmaxf(cq.x * cq.x + cq.y * cq.y + gb2 - 2.0f * (cq.x * gx + cq.y * gy), 0.0f);
                kinsert(kk, 0.1f * sqrtf(d2) - p, (unsigned)q2);
            }
        }
        #pragma unroll
        for (int d = 1; d < 64; d <<= 1) {
            u64 b0 = __shfl_xor(kk[0], d, 64);
            u64 b1 = __shfl_xor(kk[1], d, 64);
            u64 b2_ = __shfl_xor(kk[2], d, 64);
            u64 b3 = __shfl_xor(kk[3], d, 64);
            merge4(kk, b0, b1, b2_, b3);
        }
    }
    if (lane < 4) {
        u64 sel = (lane == 0) ? kk[0] : (lane == 1) ? kk[1] : (lane == 2) ? kk[2] : kk[3];
        int idx = m ? (int)(sel & 0xFFFFFFFFull) : lane;
        out[((size_t)(b * 4 + lane) << 10) + g] = idx;
    }
}

extern "C" void kernel_launch(void* const* d_in, const int* in_sizes, int n_in,
                              void* d_out, int out_size, void* d_ws, size_t ws_size,
                              hipStream_t stream) {
    const float* pred_coords = (const float*)d_in[0];
    const float* pred_logits = (const float*)d_in[1];
    const float* gt_coords   = (const float*)d_in[2];
    const int*   gt_labels   = (const int*)d_in[3];
    const int*   gt_masks    = (const int*)d_in[4];
    int* out = (int*)d_out;

    char* ws = (char*)d_ws;
    unsigned* ccount = (unsigned*)(ws + 0);      // 40*64 u32 = 10 KB, fully rewritten each call
    u64*      clist  = (u64*)(ws + 16384);       // 40*128*64 u64 = 2.62 MB, read only where valid

    prune_kernel<<<BS * 64, THREADS, 0, stream>>>(pred_logits, ccount, clist);
    match_kernel<<<BS * NG / 4, THREADS, 0, stream>>>(
        pred_coords, pred_logits, gt_coords, gt_labels, gt_masks, ccount, clist, out);
}